// Round 4
// baseline (132.788 us; speedup 1.0000x reference)
//
#include <hip/hip_runtime.h>

#define SIGMA 10.0f
#define RHO   28.0f
#define DT    0.01f
static constexpr float BETA = (float)(8.0 / 3.0);
// ln(sqrt(d)) = 0.5 * ln(2) * log2(d)
#define HALF_LN2 0.34657359028f

__device__ __forceinline__ void lorenz_f(float x, float y, float z,
                                         float& dx, float& dy, float& dz) {
    dx = SIGMA * (y - x);
    dy = x * (RHO - z) - y;
    dz = x * y - BETA * z;
}

__global__ __launch_bounds__(256)
void lya_spec_kernel(const float* __restrict__ xin,
                     const float* __restrict__ ts,
                     float* __restrict__ out,
                     int B, int T) {
    int b = blockIdx.x * blockDim.x + threadIdx.x;
    if (b >= B) return;

    float x = xin[b];
    float y = xin[B + b];
    float z = xin[2 * B + b];

    // Q rows (row-major), init = I.  Q must stay normalized each step:
    // J@Q mixes ROWS of Q (contraction over the row index), so rows must
    // have equal scale for the dt*J off-diagonal coupling to be correct
    // (R2 post-mortem: J@diag(s)@Q != diag(s)@J@Q).
    float q00 = 1.f, q01 = 0.f, q02 = 0.f;
    float q10 = 0.f, q11 = 1.f, q12 = 0.f;
    float q20 = 0.f, q21 = 0.f, q22 = 1.f;

    // Running products of per-step Gram diagonals.  Per-step d_ii is in
    // [e^-0.6, e^+0.4]; over 64 steps p_i stays within ~[1e-20, 6e7] --
    // safe in fp32.  The reference running average telescopes exactly
    // (t_k + dt == t_{k+1}) to lya_i = 0.5*ln(p_i)/(ts[T-1]+dt), so the
    // per-step logs collapse into one log at the end.
    float p0 = 1.f, p1 = 1.f, p2 = 1.f;

    for (int it = 0; it < T; ++it) {
        // ---- RK4 (faithful to reference bug: k4 at x + dt*k2) ----
        float k1x, k1y, k1z, k2x, k2y, k2z, k3x, k3y, k3z, k4x, k4y, k4z;
        lorenz_f(x, y, z, k1x, k1y, k1z);
        const float h = DT * 0.5f;
        lorenz_f(x + h * k1x, y + h * k1y, z + h * k1z, k2x, k2y, k2z);
        lorenz_f(x + h * k2x, y + h * k2y, z + h * k2z, k3x, k3y, k3z);
        lorenz_f(x + DT * k2x, y + DT * k2y, z + DT * k2z, k4x, k4y, k4z);
        const float sixth = (float)(1.0 / 6.0);
        x = x + DT * (k1x + 2.0f * k2x + 2.0f * k3x + k4x) * sixth;
        y = y + DT * (k1y + 2.0f * k2y + 2.0f * k3y + k4y) * sixth;
        z = z + DT * (k1z + 2.0f * k2z + 2.0f * k3z + k4z) * sixth;

        // ---- tangent propagator J = I + dt * Jac(x) ----
        const float j00 = 1.0f + DT * (-SIGMA);
        const float j01 = DT * SIGMA;
        // j02 = 0
        const float j10 = DT * (RHO - z);
        const float j11 = 1.0f + DT * (-1.0f);
        const float j12 = DT * (-x);
        const float j20 = DT * y;
        const float j21 = DT * x;
        const float j22 = 1.0f + DT * (-BETA);

        // ---- Q = J @ Q (per trajectory 3x3) ----
        float n00 = j00 * q00 + j01 * q10;
        float n01 = j00 * q01 + j01 * q11;
        float n02 = j00 * q02 + j01 * q12;
        float n10 = j10 * q00 + j11 * q10 + j12 * q20;
        float n11 = j10 * q01 + j11 * q11 + j12 * q21;
        float n12 = j10 * q02 + j11 * q12 + j12 * q22;
        float n20 = j20 * q00 + j21 * q10 + j22 * q20;
        float n21 = j20 * q01 + j21 * q11 + j22 * q21;
        float n22 = j20 * q02 + j21 * q12 + j22 * q22;

        // ---- MGS projections (in-place torch semantics) ----
        const float d00 = n00 * n00 + n01 * n01 + n02 * n02;
        const float rd00 = __builtin_amdgcn_rcpf(d00);

        const float d01 = n00 * n10 + n01 * n11 + n02 * n12;
        const float c01 = d01 * rd00;
        float r10 = n10 - c01 * n00;
        float r11 = n11 - c01 * n01;
        float r12 = n12 - c01 * n02;

        const float d02 = n00 * n20 + n01 * n21 + n02 * n22;
        const float c02 = d02 * rd00;
        float a0 = n20 - c02 * n00;
        float a1 = n21 - c02 * n01;
        float a2 = n22 - c02 * n02;

        const float d11 = r10 * r10 + r11 * r11 + r12 * r12;
        const float d1a = r10 * a0 + r11 * a1 + r12 * a2;
        const float c12 = d1a * __builtin_amdgcn_rcpf(d11);
        float r20 = a0 - c12 * r10;
        float r21 = a1 - c12 * r11;
        float r22 = a2 - c12 * r12;

        const float d22 = r20 * r20 + r21 * r21 + r22 * r22;

        // ---- accumulate Gram-diagonal products (replaces per-step logs) ----
        p0 *= d00;
        p1 *= d11;
        p2 *= d22;

        // ---- normalize rows via rsqrt-multiply ----
        const float rn0 = __builtin_amdgcn_rsqf(d00);
        const float rn1 = __builtin_amdgcn_rsqf(d11);
        const float rn2 = __builtin_amdgcn_rsqf(d22);

        q00 = n00 * rn0; q01 = n01 * rn0; q02 = n02 * rn0;
        q10 = r10 * rn1; q11 = r11 * rn1; q12 = r12 * rn1;
        q20 = r20 * rn2; q21 = r21 * rn2; q22 = r22 * rn2;
    }

    // ---- epilogue: lya_i = 0.5*ln(p_i) / (T*dt) ----
    const float denom = ts[T - 1] + DT;          // matches reference fp32 value
    const float rden = __builtin_amdgcn_rcpf(denom) * HALF_LN2;
    const float l0 = __builtin_amdgcn_logf(p0) * rden;
    const float l1 = __builtin_amdgcn_logf(p1) * rden;
    const float l2 = __builtin_amdgcn_logf(p2) * rden;

    // outputs: lya [3,B] then xf [3,B]
    out[b]         = l0;
    out[B + b]     = l1;
    out[2 * B + b] = l2;
    out[3 * B + b] = x;
    out[4 * B + b] = y;
    out[5 * B + b] = z;
}

extern "C" void kernel_launch(void* const* d_in, const int* in_sizes, int n_in,
                              void* d_out, int out_size, void* d_ws, size_t ws_size,
                              hipStream_t stream) {
    const float* xin = (const float*)d_in[0];
    const float* ts  = (const float*)d_in[1];
    float* out = (float*)d_out;

    const int B = in_sizes[0] / 3;   // x is [3, B]
    const int T = in_sizes[1];       // 64

    const int block = 256;
    const int grid = (B + block - 1) / block;
    lya_spec_kernel<<<grid, block, 0, stream>>>(xin, ts, out, B, T);
}

// Round 5
// 106.068 us; speedup vs baseline: 1.2519x; 1.2519x over previous
//
#include <hip/hip_runtime.h>

#define SIGMA 10.0f
#define RHO   28.0f
#define DT    0.01f
static constexpr float BETA = (float)(8.0 / 3.0);
// ln(sqrt(d)) = 0.5 * ln(2) * log2(d)
#define HALF_LN2 0.34657359028f

// ---- packed float2 helpers (component-wise; SLP-packs to v_pk_* on gfx950) ----
__device__ __forceinline__ float2 p2(float a, float b) { return make_float2(a, b); }
__device__ __forceinline__ float2 padd(float2 a, float2 b) { return p2(a.x + b.x, a.y + b.y); }
__device__ __forceinline__ float2 psub(float2 a, float2 b) { return p2(a.x - b.x, a.y - b.y); }
__device__ __forceinline__ float2 pmul(float2 a, float2 b) { return p2(a.x * b.x, a.y * b.y); }
__device__ __forceinline__ float2 pfma(float2 a, float2 b, float2 c) {
    return p2(fmaf(a.x, b.x, c.x), fmaf(a.y, b.y, c.y));
}
__device__ __forceinline__ float2 psmul(float s, float2 a) { return p2(s * a.x, s * a.y); }
__device__ __forceinline__ float2 psfma(float s, float2 a, float2 c) {
    return p2(fmaf(s, a.x, c.x), fmaf(s, a.y, c.y));
}
__device__ __forceinline__ float2 prcp(float2 a) {
    return p2(__builtin_amdgcn_rcpf(a.x), __builtin_amdgcn_rcpf(a.y));
}
__device__ __forceinline__ float2 prsq(float2 a) {
    return p2(__builtin_amdgcn_rsqf(a.x), __builtin_amdgcn_rsqf(a.y));
}
// dot3: a0*b0 + a1*b1 + a2*b2 (component-wise over the pair)
__device__ __forceinline__ float2 pdot3(float2 a0, float2 a1, float2 a2,
                                        float2 b0, float2 b1, float2 b2) {
    return pfma(a2, b2, pfma(a1, b1, pmul(a0, b0)));
}

__device__ __forceinline__ void lorenz_p(float2 x, float2 y, float2 z,
                                         float2& dx, float2& dy, float2& dz) {
    dx = psmul(SIGMA, psub(y, x));                    // sigma*(y-x)
    // x*(rho-z) - y
    float2 rz = p2(RHO - z.x, RHO - z.y);
    dy = psub(pmul(x, rz), y);
    // x*y - beta*z
    dz = psub(pmul(x, y), psmul(BETA, z));
}

__global__ __launch_bounds__(256, 2)
void lya_spec_kernel(const float* __restrict__ xin,
                     const float* __restrict__ ts,
                     float* __restrict__ out,
                     int B, int T) {
    const int i = blockIdx.x * blockDim.x + threadIdx.x;   // pair index
    if (2 * i >= B) return;

    // two trajectories per thread: elements 2i, 2i+1 of each row
    float2 x = ((const float2*)(xin))[i];
    float2 y = ((const float2*)(xin + B))[i];
    float2 z = ((const float2*)(xin + 2 * B))[i];

    // Q rows (row-major), init = I; normalized every step (required: J@Q
    // contracts over Q's row index — see R2 post-mortem).
    float2 q00 = p2(1.f, 1.f), q01 = p2(0.f, 0.f), q02 = p2(0.f, 0.f);
    float2 q10 = p2(0.f, 0.f), q11 = p2(1.f, 1.f), q12 = p2(0.f, 0.f);
    float2 q20 = p2(0.f, 0.f), q21 = p2(0.f, 0.f), q22 = p2(1.f, 1.f);

    // Running products of per-step Gram diagonals (d_ii in [e^-0.6, e^0.4];
    // 64-step product within ~[1e-20, 6e7] — fp32-safe).  Reference's
    // running average telescopes exactly to 0.5*ln(p_i)/(ts[T-1]+dt).
    float2 pr0 = p2(1.f, 1.f), pr1 = p2(1.f, 1.f), pr2 = p2(1.f, 1.f);

    for (int it = 0; it < T; ++it) {
        // ---- RK4 (faithful to reference bug: k4 at x + dt*k2) ----
        float2 k1x, k1y, k1z, k2x, k2y, k2z, k3x, k3y, k3z, k4x, k4y, k4z;
        lorenz_p(x, y, z, k1x, k1y, k1z);
        const float h = DT * 0.5f;
        lorenz_p(psfma(h, k1x, x), psfma(h, k1y, y), psfma(h, k1z, z), k2x, k2y, k2z);
        lorenz_p(psfma(h, k2x, x), psfma(h, k2y, y), psfma(h, k2z, z), k3x, k3y, k3z);
        lorenz_p(psfma(DT, k2x, x), psfma(DT, k2y, y), psfma(DT, k2z, z), k4x, k4y, k4z);
        const float c6 = DT * (float)(1.0 / 6.0);
        // x += (dt/6) * (k1 + 2k2 + 2k3 + k4)
        x = psfma(c6, padd(padd(k1x, k4x), psmul(2.f, padd(k2x, k3x))), x);
        y = psfma(c6, padd(padd(k1y, k4y), psmul(2.f, padd(k2y, k3y))), y);
        z = psfma(c6, padd(padd(k1z, k4z), psmul(2.f, padd(k2z, k3z))), z);

        // ---- tangent propagator J = I + dt*Jac(x) ----
        const float j00 = 1.0f - DT * SIGMA;
        const float j01 = DT * SIGMA;
        const float j11 = 1.0f - DT;
        const float j22 = 1.0f - DT * BETA;
        float2 j10 = p2(DT * (RHO - z.x), DT * (RHO - z.y));
        float2 j12 = psmul(-DT, x);
        float2 j20 = psmul(DT, y);
        float2 j21 = psmul(DT, x);

        // ---- Q = J @ Q ----
        float2 n00 = psfma(j01, q10, psmul(j00, q00));
        float2 n01 = psfma(j01, q11, psmul(j00, q01));
        float2 n02 = psfma(j01, q12, psmul(j00, q02));
        float2 n10 = pfma(j12, q20, psfma(j11, q10, pmul(j10, q00)));
        float2 n11 = pfma(j12, q21, psfma(j11, q11, pmul(j10, q01)));
        float2 n12 = pfma(j12, q22, psfma(j11, q12, pmul(j10, q02)));
        float2 n20 = psfma(j22, q20, pfma(j21, q10, pmul(j20, q00)));
        float2 n21 = psfma(j22, q21, pfma(j21, q11, pmul(j20, q01)));
        float2 n22 = psfma(j22, q22, pfma(j21, q12, pmul(j20, q02)));

        // ---- MGS projections (in-place torch semantics) ----
        float2 d00 = pdot3(n00, n01, n02, n00, n01, n02);
        float2 rd00 = prcp(d00);

        float2 d01 = pdot3(n00, n01, n02, n10, n11, n12);
        float2 c01 = pmul(d01, rd00);
        float2 r10 = psub(n10, pmul(c01, n00));
        float2 r11 = psub(n11, pmul(c01, n01));
        float2 r12 = psub(n12, pmul(c01, n02));

        float2 d02 = pdot3(n00, n01, n02, n20, n21, n22);
        float2 c02 = pmul(d02, rd00);
        float2 a0 = psub(n20, pmul(c02, n00));
        float2 a1 = psub(n21, pmul(c02, n01));
        float2 a2 = psub(n22, pmul(c02, n02));

        float2 d11 = pdot3(r10, r11, r12, r10, r11, r12);
        float2 d1a = pdot3(r10, r11, r12, a0, a1, a2);
        float2 c12 = pmul(d1a, prcp(d11));
        float2 r20 = psub(a0, pmul(c12, r10));
        float2 r21 = psub(a1, pmul(c12, r11));
        float2 r22 = psub(a2, pmul(c12, r12));

        float2 d22 = pdot3(r20, r21, r22, r20, r21, r22);

        // ---- accumulate Gram-diagonal products (replaces per-step logs) ----
        pr0 = pmul(pr0, d00);
        pr1 = pmul(pr1, d11);
        pr2 = pmul(pr2, d22);

        // ---- normalize rows via rsqrt-multiply ----
        float2 rn0 = prsq(d00);
        float2 rn1 = prsq(d11);
        float2 rn2 = prsq(d22);

        q00 = pmul(n00, rn0); q01 = pmul(n01, rn0); q02 = pmul(n02, rn0);
        q10 = pmul(r10, rn1); q11 = pmul(r11, rn1); q12 = pmul(r12, rn1);
        q20 = pmul(r20, rn2); q21 = pmul(r21, rn2); q22 = pmul(r22, rn2);
    }

    // ---- epilogue: lya_i = 0.5*ln(pr_i) / (T*dt) ----
    const float denom = ts[T - 1] + DT;            // matches reference fp32 value
    const float rden = __builtin_amdgcn_rcpf(denom) * HALF_LN2;
    float2 l0 = p2(__builtin_amdgcn_logf(pr0.x) * rden, __builtin_amdgcn_logf(pr0.y) * rden);
    float2 l1 = p2(__builtin_amdgcn_logf(pr1.x) * rden, __builtin_amdgcn_logf(pr1.y) * rden);
    float2 l2 = p2(__builtin_amdgcn_logf(pr2.x) * rden, __builtin_amdgcn_logf(pr2.y) * rden);

    // outputs: lya [3,B] then xf [3,B]
    ((float2*)(out))[i]          = l0;
    ((float2*)(out + B))[i]      = l1;
    ((float2*)(out + 2 * B))[i]  = l2;
    ((float2*)(out + 3 * B))[i]  = x;
    ((float2*)(out + 4 * B))[i]  = y;
    ((float2*)(out + 5 * B))[i]  = z;
}

extern "C" void kernel_launch(void* const* d_in, const int* in_sizes, int n_in,
                              void* d_out, int out_size, void* d_ws, size_t ws_size,
                              hipStream_t stream) {
    const float* xin = (const float*)d_in[0];
    const float* ts  = (const float*)d_in[1];
    float* out = (float*)d_out;

    const int B = in_sizes[0] / 3;   // x is [3, B]
    const int T = in_sizes[1];       // 64

    const int block = 256;
    const int pairs = B / 2;         // B = 262144, even
    const int grid = (pairs + block - 1) / block;
    lya_spec_kernel<<<grid, block, 0, stream>>>(xin, ts, out, B, T);
}

// Round 6
// 87.868 us; speedup vs baseline: 1.5112x; 1.2071x over previous
//
#include <hip/hip_runtime.h>

#define SIGMA 10.0f
#define RHO   28.0f
#define DT    0.01f
static constexpr float BETA = (float)(8.0 / 3.0);
// ln(sqrt(d)) = 0.5 * ln(2) * log2(d)
#define HALF_LN2 0.34657359028f

// Native clang vector type -> genuine <2 x float> IR -> v_pk_*_f32 on gfx950
typedef float v2 __attribute__((ext_vector_type(2)));

__device__ __forceinline__ v2 vsplat(float s) { v2 r; r.x = s; r.y = s; return r; }
__device__ __forceinline__ v2 vfma(v2 a, v2 b, v2 c) {
    return __builtin_elementwise_fma(a, b, c);
}
__device__ __forceinline__ v2 sfma(float s, v2 a, v2 c) {   // s*a + c
    return __builtin_elementwise_fma(vsplat(s), a, c);
}
// dot3 (componentwise over the pair): a0*b0 + a1*b1 + a2*b2
__device__ __forceinline__ v2 vdot3(v2 a0, v2 a1, v2 a2, v2 b0, v2 b1, v2 b2) {
    return vfma(a2, b2, vfma(a1, b1, a0 * b0));
}
__device__ __forceinline__ v2 vrsq(v2 a) {
    v2 r;
    r.x = __builtin_amdgcn_rsqf(a.x);
    r.y = __builtin_amdgcn_rsqf(a.y);
    return r;
}

__device__ __forceinline__ void lorenz_v(v2 x, v2 y, v2 z,
                                         v2& dx, v2& dy, v2& dz) {
    dx = vsplat(SIGMA) * (y - x);              // sigma*(y-x)
    dy = x * (vsplat(RHO) - z) - y;            // x*(rho-z) - y
    dz = x * y - vsplat(BETA) * z;             // x*y - beta*z
}

__global__ __launch_bounds__(256, 2)
void lya_spec_kernel(const float* __restrict__ xin,
                     const float* __restrict__ ts,
                     float* __restrict__ out,
                     int B, int T) {
    const int i = blockIdx.x * blockDim.x + threadIdx.x;   // pair index
    if (2 * i >= B) return;

    // two trajectories per thread: elements 2i, 2i+1 of each row
    v2 x = ((const v2*)(xin))[i];
    v2 y = ((const v2*)(xin + B))[i];
    v2 z = ((const v2*)(xin + 2 * B))[i];

    // Q rows (row-major), init = I; normalized every step (required: J@Q
    // contracts over Q's row index — see R2 post-mortem).
    v2 q00 = vsplat(1.f), q01 = vsplat(0.f), q02 = vsplat(0.f);
    v2 q10 = vsplat(0.f), q11 = vsplat(1.f), q12 = vsplat(0.f);
    v2 q20 = vsplat(0.f), q21 = vsplat(0.f), q22 = vsplat(1.f);

    // Running products of per-step Gram diagonals (d_ii in [e^-0.6, e^0.4];
    // 64-step product in ~[1e-20, 6e7] — fp32-safe).  Reference's running
    // average telescopes exactly to 0.5*ln(p_i)/(ts[T-1]+dt).
    v2 pr0 = vsplat(1.f), pr1 = vsplat(1.f), pr2 = vsplat(1.f);

    for (int it = 0; it < T; ++it) {
        // ---- RK4 (faithful to reference bug: k4 at x + dt*k2) ----
        v2 k1x, k1y, k1z, k2x, k2y, k2z, k3x, k3y, k3z, k4x, k4y, k4z;
        lorenz_v(x, y, z, k1x, k1y, k1z);
        const float h = DT * 0.5f;
        lorenz_v(sfma(h, k1x, x), sfma(h, k1y, y), sfma(h, k1z, z), k2x, k2y, k2z);
        lorenz_v(sfma(h, k2x, x), sfma(h, k2y, y), sfma(h, k2z, z), k3x, k3y, k3z);
        lorenz_v(sfma(DT, k2x, x), sfma(DT, k2y, y), sfma(DT, k2z, z), k4x, k4y, k4z);
        const float c6 = DT * (float)(1.0 / 6.0);
        // x += (dt/6) * (k1 + 2k2 + 2k3 + k4)
        x = sfma(c6, (k1x + k4x) + vsplat(2.f) * (k2x + k3x), x);
        y = sfma(c6, (k1y + k4y) + vsplat(2.f) * (k2y + k3y), y);
        z = sfma(c6, (k1z + k4z) + vsplat(2.f) * (k2z + k3z), z);

        // ---- tangent propagator J = I + dt*Jac(x) ----
        const float j00 = 1.0f - DT * SIGMA;
        const float j01 = DT * SIGMA;
        const float j11 = 1.0f - DT;
        const float j22 = 1.0f - DT * BETA;
        v2 j10 = vsplat(DT) * (vsplat(RHO) - z);
        v2 j12 = vsplat(-DT) * x;
        v2 j20 = vsplat(DT) * y;
        v2 j21 = vsplat(DT) * x;

        // ---- Q = J @ Q ----
        v2 n00 = sfma(j01, q10, vsplat(j00) * q00);
        v2 n01 = sfma(j01, q11, vsplat(j00) * q01);
        v2 n02 = sfma(j01, q12, vsplat(j00) * q02);
        v2 n10 = vfma(j12, q20, sfma(j11, q10, j10 * q00));
        v2 n11 = vfma(j12, q21, sfma(j11, q11, j10 * q01));
        v2 n12 = vfma(j12, q22, sfma(j11, q12, j10 * q02));
        v2 n20 = sfma(j22, q20, vfma(j21, q10, j20 * q00));
        v2 n21 = sfma(j22, q21, vfma(j21, q11, j20 * q01));
        v2 n22 = sfma(j22, q22, vfma(j21, q12, j20 * q02));

        // ---- MGS projections (in-place torch semantics) ----
        // trans-op diet: 1/d == rsq(d)^2 (~2 ulp), so only 3 rsq per step.
        v2 d00 = vdot3(n00, n01, n02, n00, n01, n02);
        v2 rn0 = vrsq(d00);
        v2 rd00 = rn0 * rn0;

        v2 d01 = vdot3(n00, n01, n02, n10, n11, n12);
        v2 c01 = d01 * rd00;
        v2 r10 = n10 - c01 * n00;
        v2 r11 = n11 - c01 * n01;
        v2 r12 = n12 - c01 * n02;

        v2 d02 = vdot3(n00, n01, n02, n20, n21, n22);
        v2 c02 = d02 * rd00;
        v2 a0 = n20 - c02 * n00;
        v2 a1 = n21 - c02 * n01;
        v2 a2 = n22 - c02 * n02;

        v2 d11 = vdot3(r10, r11, r12, r10, r11, r12);
        v2 rn1 = vrsq(d11);
        v2 d1a = vdot3(r10, r11, r12, a0, a1, a2);
        v2 c12 = d1a * (rn1 * rn1);
        v2 r20 = a0 - c12 * r10;
        v2 r21 = a1 - c12 * r11;
        v2 r22 = a2 - c12 * r12;

        v2 d22 = vdot3(r20, r21, r22, r20, r21, r22);
        v2 rn2 = vrsq(d22);

        // ---- accumulate Gram-diagonal products (replaces per-step logs) ----
        pr0 = pr0 * d00;
        pr1 = pr1 * d11;
        pr2 = pr2 * d22;

        // ---- normalize rows via rsqrt-multiply ----
        q00 = n00 * rn0; q01 = n01 * rn0; q02 = n02 * rn0;
        q10 = r10 * rn1; q11 = r11 * rn1; q12 = r12 * rn1;
        q20 = r20 * rn2; q21 = r21 * rn2; q22 = r22 * rn2;
    }

    // ---- epilogue: lya_i = 0.5*ln(pr_i) / (T*dt) ----
    const float denom = ts[T - 1] + DT;            // matches reference fp32 value
    const float rden = __builtin_amdgcn_rcpf(denom) * HALF_LN2;
    v2 l0, l1, l2;
    l0.x = __builtin_amdgcn_logf(pr0.x) * rden;
    l0.y = __builtin_amdgcn_logf(pr0.y) * rden;
    l1.x = __builtin_amdgcn_logf(pr1.x) * rden;
    l1.y = __builtin_amdgcn_logf(pr1.y) * rden;
    l2.x = __builtin_amdgcn_logf(pr2.x) * rden;
    l2.y = __builtin_amdgcn_logf(pr2.y) * rden;

    // outputs: lya [3,B] then xf [3,B]
    ((v2*)(out))[i]          = l0;
    ((v2*)(out + B))[i]      = l1;
    ((v2*)(out + 2 * B))[i]  = l2;
    ((v2*)(out + 3 * B))[i]  = x;
    ((v2*)(out + 4 * B))[i]  = y;
    ((v2*)(out + 5 * B))[i]  = z;
}

extern "C" void kernel_launch(void* const* d_in, const int* in_sizes, int n_in,
                              void* d_out, int out_size, void* d_ws, size_t ws_size,
                              hipStream_t stream) {
    const float* xin = (const float*)d_in[0];
    const float* ts  = (const float*)d_in[1];
    float* out = (float*)d_out;

    const int B = in_sizes[0] / 3;   // x is [3, B]
    const int T = in_sizes[1];       // 64

    const int block = 256;
    const int pairs = B / 2;         // B = 262144, even
    const int grid = (pairs + block - 1) / block;
    lya_spec_kernel<<<grid, block, 0, stream>>>(xin, ts, out, B, T);
}